// Round 10
// baseline (202.809 us; speedup 1.0000x reference)
//
#include <hip/hip_runtime.h>

#define DEV __device__ __forceinline__

typedef __bf16 bf16x8 __attribute__((ext_vector_type(8)));
typedef float f32x4 __attribute__((ext_vector_type(4)));
typedef unsigned u32x4 __attribute__((ext_vector_type(4)));
typedef unsigned short ushort_t;

static constexpr int EMBED = 1024;
static constexpr int NHEAD = 16;
static constexpr int HDIM  = 64;
static constexpr int S_    = 2048;
static constexpr float SCALE_L2E = 0.125f * 1.44269504088896340736f; // (1/sqrt(64))*log2(e)

DEV ushort_t f2bf(float f) {
  unsigned u = __builtin_bit_cast(unsigned, f);
  unsigned r = (u + 0x7fffu + ((u >> 16) & 1u)) >> 16;
  return (ushort_t)r;
}

// Bit-exchange between register-index bit R (a vs b) and a lane bit, built
// from __shfl_xor + select (compiler-modeled cross-lane ops: hazard-safe,
// unlike raw inline-asm v_permlane*_swap which caused scheduling-dependent
// corruption in R5/R7/R8).
// swap32: new(R=x, L5=y) = old(R=y, L5=x)
DEV void swap32(int lane, unsigned& a, unsigned& b) {
  unsigned ta = (unsigned)__shfl_xor((int)a, 32);
  unsigned tb = (unsigned)__shfl_xor((int)b, 32);
  bool hi = (lane & 32) != 0;
  unsigned na = hi ? tb : a;
  unsigned nb_ = hi ? b : ta;
  a = na; b = nb_;
}
// swap16: new(R=x, L4=y) = old(R=y, L4=x)
DEV void swap16(int lane, unsigned& a, unsigned& b) {
  unsigned ta = (unsigned)__shfl_xor((int)a, 16);
  unsigned tb = (unsigned)__shfl_xor((int)b, 16);
  bool hi = (lane & 16) != 0;
  unsigned na = hi ? tb : a;
  unsigned nb_ = hi ? b : ta;
  a = na; b = nb_;
}

// async global->LDS, 16B per lane; LDS dest is wave-uniform base + lane*16
#define GLOAD_LDS16(g, l)                                                   \
  __builtin_amdgcn_global_load_lds(                                         \
      (const __attribute__((address_space(1))) unsigned int*)(g),           \
      (__attribute__((address_space(3))) unsigned int*)(l), 16, 0, 0)

// ---------------------------------------------------------------------------
// fp32 -> bf16 conversion of x and the four weight matrices
// ---------------------------------------------------------------------------
__global__ __launch_bounds__(256) void convert_kernel(
    const float* __restrict__ x,
    const float* __restrict__ wq, const float* __restrict__ wk,
    const float* __restrict__ wv, const float* __restrict__ wo,
    ushort_t* __restrict__ xb, ushort_t* __restrict__ wqb,
    ushort_t* __restrict__ wkb, ushort_t* __restrict__ wvb,
    ushort_t* __restrict__ wob) {
  size_t i = ((size_t)blockIdx.x * blockDim.x + threadIdx.x) * 4;
  const float* src; ushort_t* dst; size_t off;
  if (i < 4194304u)      { src = x;  dst = xb;  off = i; }
  else if (i < 5242880u) { src = wq; dst = wqb; off = i - 4194304u; }
  else if (i < 6291456u) { src = wk; dst = wkb; off = i - 5242880u; }
  else if (i < 7340032u) { src = wv; dst = wvb; off = i - 6291456u; }
  else                   { src = wo; dst = wob; off = i - 7340032u; }
  float4 v = *(const float4*)(src + off);
  ushort4 o;
  o.x = f2bf(v.x); o.y = f2bf(v.y); o.z = f2bf(v.z); o.w = f2bf(v.w);
  *(ushort4*)(dst + off) = o;
}

// ---------------------------------------------------------------------------
// Merged QKV GEMM, 1-D grid of 768 blocks (verified-green R4 structure):
//   bid <256 : Q = xb @ Wq^T  -> [B,H,S,D], (acc+bias)*mask*SCALE_L2E
//   bid <512 : K = xb @ Wk^T  -> [B,H,S,D], (acc+bias)*mask
//   else     : V^T (A=Wv, B=xb) -> [B,H,D,S], acc+bias
// 128x128 tile, BK=64, 4 waves, global_load_lds double-buffered 2-phase
// ---------------------------------------------------------------------------
__global__ __launch_bounds__(256) void qkv_kernel(
    const ushort_t* __restrict__ xb, const ushort_t* __restrict__ wqb,
    const ushort_t* __restrict__ wkb, const ushort_t* __restrict__ wvb,
    const float* __restrict__ bq, const float* __restrict__ bk,
    const float* __restrict__ bv, const int* __restrict__ mask,
    ushort_t* __restrict__ qo, ushort_t* __restrict__ ko,
    ushort_t* __restrict__ vto) {
  __shared__ __align__(16) unsigned char ldsA[2][16384];
  __shared__ __align__(16) unsigned char ldsB[2][16384];
  __shared__ float maskf[2][128];

  const int bid  = blockIdx.x;
  const int tid  = threadIdx.x;
  const int lane = tid & 63;
  const int w    = tid >> 6;
  const int wm   = (w >> 1) * 64;
  const int wn   = (w & 1) * 64;
  const int rl   = lane & 15;
  const int kg   = lane >> 4;

  int mode, ar0, br0;
  const ushort_t *A, *Bm;
  const float* bias;
  if (bid < 512) {
    mode = bid >> 8;                 // 0=Q, 1=K
    int t = bid & 255;
    ar0 = (t & 31) * 128;            // x rows
    br0 = (t >> 5) * 128;            // weight rows
    A = xb; Bm = mode ? wkb : wqb; bias = mode ? bk : bq;
  } else {
    mode = 2;
    int t = bid - 512;
    ar0 = (t & 7) * 128;             // weight rows
    br0 = (t >> 3) * 128;            // x rows
    A = wvb; Bm = xb; bias = bv;
  }

  if (mode < 2) {
    int hl = tid >> 7, sl = tid & 127;
    int m = ar0 + sl;
    int b = m >> 11, s = m & 2047;
    int h = (br0 >> 6) + hl;
    maskf[hl][sl] = (float)mask[((size_t)b * NHEAD + h) * S_ + s];
  }

  f32x4 acc[4][4];
#pragma unroll
  for (int i = 0; i < 4; ++i)
#pragma unroll
    for (int j = 0; j < 4; ++j) acc[i][j] = f32x4{0.f, 0.f, 0.f, 0.f};

  auto STAGE = [&](int kt, int bsel) {
    const int k0 = kt * 64;
#pragma unroll
    for (int s = 0; s < 8; ++s) {
      const int basev = s * 256 + w * 64;   // wave-uniform
      const int Lb = basev & 1023;
      const int L = Lb + lane;
      const int row = L >> 3;
      const int gu = (L & 7) ^ (row & 7);
      if (s < 4) {
        GLOAD_LDS16(A + (size_t)(ar0 + row) * EMBED + k0 + gu * 8, &ldsA[bsel][Lb * 16]);
      } else {
        GLOAD_LDS16(Bm + (size_t)(br0 + row) * EMBED + k0 + gu * 8, &ldsB[bsel][Lb * 16]);
      }
    }
  };

  STAGE(0, 0);
  __syncthreads();
  int bsel = 0;
  for (int kt = 0; kt < 16; ++kt) {
    if (kt < 15) STAGE(kt + 1, bsel ^ 1);
#pragma unroll
    for (int kk = 0; kk < 2; ++kk) {
      bf16x8 af[4], bfr[4];
#pragma unroll
      for (int mb = 0; mb < 4; ++mb) {
        const int row = wm + mb * 16 + rl;
        const int off = (kk * 64 + kg * 16) ^ ((row & 7) << 4);
        af[mb] = *(const bf16x8*)(ldsA[bsel] + row * 128 + off);
      }
#pragma unroll
      for (int nb = 0; nb < 4; ++nb) {
        const int row = wn + nb * 16 + rl;
        const int off = (kk * 64 + kg * 16) ^ ((row & 7) << 4);
        bfr[nb] = *(const bf16x8*)(ldsB[bsel] + row * 128 + off);
      }
#pragma unroll
      for (int mb = 0; mb < 4; ++mb)
#pragma unroll
        for (int nb = 0; nb < 4; ++nb)
          acc[mb][nb] = __builtin_amdgcn_mfma_f32_16x16x32_bf16(
              af[mb], bfr[nb], acc[mb][nb], 0, 0, 0);
    }
    __syncthreads();
    bsel ^= 1;
  }

  // epilogue — D layout: row(A idx)=(lane>>4)*4+r, col(B idx)=lane&15
#pragma unroll
  for (int mb = 0; mb < 4; ++mb)
#pragma unroll
    for (int nb = 0; nb < 4; ++nb)
#pragma unroll
      for (int r = 0; r < 4; ++r) {
        int row_l = wm + mb * 16 + kg * 4 + r;
        int col_l = wn + nb * 16 + rl;
        float v = acc[mb][nb][r];
        if (mode < 2) {
          int m = ar0 + row_l, n = br0 + col_l;
          v = (v + bias[n]) * maskf[col_l >> 6][row_l];
          if (mode == 0) v *= SCALE_L2E;
          int b = m >> 11, s = m & 2047, h = n >> 6, d = n & 63;
          ushort_t* o = mode ? ko : qo;
          o[(((size_t)(b * NHEAD + h)) * S_ + s) * HDIM + d] = f2bf(v);
        } else {
          int n = ar0 + row_l, m = br0 + col_l;
          v += bias[n];
          int b = m >> 11, s = m & 2047, h = n >> 6, d = n & 63;
          vto[(((size_t)(b * NHEAD + h)) * HDIM + d) * S_ + s] = f2bf(v);
        }
      }
}

// ---------------------------------------------------------------------------
// O projection GEMM: out[m][n] = aob[m][:] . Wo[n][:] + bo[n]  (fp32 out)
// (verified-green R4 double-buffered structure)
// ---------------------------------------------------------------------------
__global__ __launch_bounds__(256) void gemm_o_kernel(
    const ushort_t* __restrict__ A, const ushort_t* __restrict__ Bm,
    const float* __restrict__ bias, float* __restrict__ outp) {
  __shared__ __align__(16) unsigned char ldsA[2][16384];
  __shared__ __align__(16) unsigned char ldsB[2][16384];

  const int tid  = threadIdx.x;
  const int lane = tid & 63;
  const int w    = tid >> 6;
  const int ar0  = blockIdx.x * 128;
  const int br0  = blockIdx.y * 128;
  const int wm   = (w >> 1) * 64;
  const int wn   = (w & 1) * 64;
  const int rl   = lane & 15;
  const int kg   = lane >> 4;

  f32x4 acc[4][4];
#pragma unroll
  for (int i = 0; i < 4; ++i)
#pragma unroll
    for (int j = 0; j < 4; ++j) acc[i][j] = f32x4{0.f, 0.f, 0.f, 0.f};

  auto STAGE = [&](int kt, int bsel) {
    const int k0 = kt * 64;
#pragma unroll
    for (int s = 0; s < 8; ++s) {
      const int basev = s * 256 + w * 64;
      const int Lb = basev & 1023;
      const int L = Lb + lane;
      const int row = L >> 3;
      const int gu = (L & 7) ^ (row & 7);
      if (s < 4) {
        GLOAD_LDS16(A + (size_t)(ar0 + row) * EMBED + k0 + gu * 8, &ldsA[bsel][Lb * 16]);
      } else {
        GLOAD_LDS16(Bm + (size_t)(br0 + row) * EMBED + k0 + gu * 8, &ldsB[bsel][Lb * 16]);
      }
    }
  };

  STAGE(0, 0);
  __syncthreads();
  int bsel = 0;
  for (int kt = 0; kt < 16; ++kt) {
    if (kt < 15) STAGE(kt + 1, bsel ^ 1);
#pragma unroll
    for (int kk = 0; kk < 2; ++kk) {
      bf16x8 af[4], bfr[4];
#pragma unroll
      for (int mb = 0; mb < 4; ++mb) {
        const int row = wm + mb * 16 + rl;
        const int off = (kk * 64 + kg * 16) ^ ((row & 7) << 4);
        af[mb] = *(const bf16x8*)(ldsA[bsel] + row * 128 + off);
      }
#pragma unroll
      for (int nb = 0; nb < 4; ++nb) {
        const int row = wn + nb * 16 + rl;
        const int off = (kk * 64 + kg * 16) ^ ((row & 7) << 4);
        bfr[nb] = *(const bf16x8*)(ldsB[bsel] + row * 128 + off);
      }
#pragma unroll
      for (int mb = 0; mb < 4; ++mb)
#pragma unroll
        for (int nb = 0; nb < 4; ++nb)
          acc[mb][nb] = __builtin_amdgcn_mfma_f32_16x16x32_bf16(
              af[mb], bfr[nb], acc[mb][nb], 0, 0, 0);
    }
    __syncthreads();
    bsel ^= 1;
  }

#pragma unroll
  for (int mb = 0; mb < 4; ++mb)
#pragma unroll
    for (int nb = 0; nb < 4; ++nb)
#pragma unroll
      for (int r = 0; r < 4; ++r) {
        int m = ar0 + wm + mb * 16 + kg * 4 + r;
        int n = br0 + wn + nb * 16 + rl;
        outp[(size_t)m * EMBED + n] = acc[mb][nb][r] + bias[n];
      }
}

// ---------------------------------------------------------------------------
// Flash attention, swapped-QK^T, fixed-exponent softmax (R4 structure, de-asm'd):
// logits already base-2 (scale folded into Q); p = exp2(s) overflow-free.
// P -> bf16 via compiler casts; l accumulated from the SAME quantized bf16
// values as PV uses -> rounding bias cancels exactly in o/l.
// P redistributed to MFMA-A layout in-register via shfl_xor bit-exchanges
// (no inline asm anywhere -> no unmodeled cross-lane hazards).
// grid (bh=32, qt=32); 2 waves x 32 q-rows; K/V^T tiles of 64 keys, dbuf.
// ---------------------------------------------------------------------------
__global__ __launch_bounds__(128) void attn_kernel(
    const ushort_t* __restrict__ qp, const ushort_t* __restrict__ kp,
    const ushort_t* __restrict__ vtp, ushort_t* __restrict__ ao) {
  __shared__ __align__(16) unsigned char ldsK[2][8192];
  __shared__ __align__(16) unsigned char ldsV[2][8192];

  const int tid  = threadIdx.x;
  const int lane = tid & 63;
  const int w    = tid >> 6;                  // 0..1
  const int bh   = blockIdx.x;
  const int q0   = blockIdx.y * 64 + w * 32;  // wave's q base
  const int rl   = lane & 15;
  const int kg   = lane >> 4;

  // Q fragments (B-operand): lane (rl,kg) holds Q[q=qb*16+rl][d=kk*32+kg*8..+8]
  bf16x8 qa[2][2];
#pragma unroll
  for (int qb = 0; qb < 2; ++qb)
#pragma unroll
    for (int kk = 0; kk < 2; ++kk)
      qa[qb][kk] = *(const bf16x8*)(qp + ((size_t)bh * S_ + q0 + qb * 16 + rl) * HDIM +
                                    kk * 32 + kg * 8);

  f32x4 o_acc[2][4];
#pragma unroll
  for (int qb = 0; qb < 2; ++qb)
#pragma unroll
    for (int nb = 0; nb < 4; ++nb) o_acc[qb][nb] = f32x4{0.f, 0.f, 0.f, 0.f};
  float l_run[2] = {0.f, 0.f};

  auto STAGE = [&](int kt, int bsel) {
#pragma unroll
    for (int s = 0; s < 8; ++s) {
      const int Lb = (s & 3) * 128 + w * 64;  // wave-uniform
      const int L = Lb + lane;
      const int row = L >> 3;
      const int gu = (L & 7) ^ (row & 7);
      if (s < 4) {
        GLOAD_LDS16(kp + ((size_t)bh * S_ + (size_t)kt * 64 + row) * HDIM + gu * 8,
                    &ldsK[bsel][Lb * 16]);
      } else {
        GLOAD_LDS16(vtp + ((size_t)bh * HDIM + row) * S_ + (size_t)kt * 64 + gu * 8,
                    &ldsV[bsel][Lb * 16]);
      }
    }
  };

  STAGE(0, 0);
  __syncthreads();
  int cb = 0;
  for (int kt = 0; kt < 32; ++kt) {
    if (kt < 31) STAGE(kt + 1, cb ^ 1);

    // QK^T (swapped): sa[qb][nb][r] = S^T[key=nb*16+kg*4+r][q=qb*16+rl]
    f32x4 sa[2][4];
#pragma unroll
    for (int qb = 0; qb < 2; ++qb)
#pragma unroll
      for (int nb = 0; nb < 4; ++nb) sa[qb][nb] = f32x4{0.f, 0.f, 0.f, 0.f};
#pragma unroll
    for (int nb = 0; nb < 4; ++nb) {
      const int row = nb * 16 + rl;
#pragma unroll
      for (int kk = 0; kk < 2; ++kk) {
        bf16x8 kf = *(const bf16x8*)(ldsK[cb] + row * 128 +
                                     ((kk * 64 + kg * 16) ^ ((row & 7) << 4)));
        sa[0][nb] = __builtin_amdgcn_mfma_f32_16x16x32_bf16(kf, qa[0][kk], sa[0][nb], 0, 0, 0);
        sa[1][nb] = __builtin_amdgcn_mfma_f32_16x16x32_bf16(kf, qa[1][kk], sa[1][nb], 0, 0, 0);
      }
    }

    // p = exp2(s) -> bf16 (compiler cvt); l from the SAME quantized values;
    // pack pairs; redistribute to A-frag via shfl bit-exchanges:
    //   key bits: nb=k5k4, kg=k3k2, r=k1k0 at lane (L4=k2,L5=k3), word (nb,t=k1)
    //   swap32 (k4<->L5) then swap16 (k3<->L4) -> lane (L4=k3,L5=k4),
    //   word (k2,k1), halfword k0  ==  A-frag for mfma(P, V^T)
    bf16x8 pa[2][2];
#pragma unroll
    for (int qb = 0; qb < 2; ++qb) {
      unsigned wd[4][2];
      float lac = 0.f;
#pragma unroll
      for (int nb = 0; nb < 4; ++nb)
#pragma unroll
        for (int t = 0; t < 2; ++t) {
          float p0 = __builtin_amdgcn_exp2f(sa[qb][nb][2 * t]);
          float p1 = __builtin_amdgcn_exp2f(sa[qb][nb][2 * t + 1]);
          __bf16 b0 = (__bf16)p0;
          __bf16 b1 = (__bf16)p1;
          lac += (float)b0 + (float)b1;   // bit-identical to PV's P
          unsigned u0 = (unsigned)__builtin_bit_cast(unsigned short, b0);
          unsigned u1 = (unsigned)__builtin_bit_cast(unsigned short, b1);
          wd[nb][t] = u0 | (u1 << 16);
        }
      l_run[qb] += lac;
#pragma unroll
      for (int k5 = 0; k5 < 2; ++k5)
#pragma unroll
        for (int t = 0; t < 2; ++t) {
          swap32(lane, wd[2 * k5][t], wd[2 * k5 + 1][t]);
          swap16(lane, wd[2 * k5][t], wd[2 * k5 + 1][t]);
        }
      pa[qb][0] = __builtin_bit_cast(bf16x8, u32x4{wd[0][0], wd[0][1], wd[1][0], wd[1][1]});
      pa[qb][1] = __builtin_bit_cast(bf16x8, u32x4{wd[2][0], wd[2][1], wd[3][0], wd[3][1]});
    }

    // PV: O[q][d] += P[q][key] * V^T[d][key]
#pragma unroll
    for (int nb = 0; nb < 4; ++nb) {
      const int row = nb * 16 + rl;
#pragma unroll
      for (int kk = 0; kk < 2; ++kk) {
        bf16x8 vb = *(const bf16x8*)(ldsV[cb] + row * 128 +
                                     ((kk * 64 + kg * 16) ^ ((row & 7) << 4)));
        o_acc[0][nb] = __builtin_amdgcn_mfma_f32_16x16x32_bf16(pa[0][kk], vb, o_acc[0][nb], 0, 0, 0);
        o_acc[1][nb] = __builtin_amdgcn_mfma_f32_16x16x32_bf16(pa[1][kk], vb, o_acc[1][nb], 0, 0, 0);
      }
    }

    __syncthreads();
    cb ^= 1;
  }

  // epilogue: O[q=qb*16+kg*4+r][d=nb*16+rl] / l[q]
  const int b = bh >> 4, h = bh & 15;
#pragma unroll
  for (int qb = 0; qb < 2; ++qb) {
    float lf = l_run[qb];
    lf += __shfl_xor(lf, 16);
    lf += __shfl_xor(lf, 32);   // lane rl now holds full l for q=qb*16+rl
#pragma unroll
    for (int r = 0; r < 4; ++r) {
      float lv = __shfl(lf, kg * 4 + r);
      float linv = 1.0f / lv;
      const int row = q0 + qb * 16 + kg * 4 + r;
#pragma unroll
      for (int nb = 0; nb < 4; ++nb) {
        float v = o_acc[qb][nb][r] * linv;
        ao[((size_t)b * S_ + row) * EMBED + h * HDIM + nb * 16 + rl] = f2bf(v);
      }
    }
  }
}

// ---------------------------------------------------------------------------
extern "C" void kernel_launch(void* const* d_in, const int* in_sizes, int n_in,
                              void* d_out, int out_size, void* d_ws, size_t ws_size,
                              hipStream_t stream) {
  const float* x    = (const float*)d_in[0];
  const int*   mask = (const int*)d_in[1];
  const float* Wq   = (const float*)d_in[2];
  const float* bq   = (const float*)d_in[3];
  const float* Wk   = (const float*)d_in[4];
  const float* bk   = (const float*)d_in[5];
  const float* Wv   = (const float*)d_in[6];
  const float* bv   = (const float*)d_in[7];
  const float* Wo   = (const float*)d_in[8];
  const float* bo   = (const float*)d_in[9];

  char* ws = (char*)d_ws;
  ushort_t* xb  = (ushort_t*)(ws);
  ushort_t* wqb = (ushort_t*)(ws + 8388608);
  ushort_t* wkb = (ushort_t*)(ws + 10485760);
  ushort_t* wvb = (ushort_t*)(ws + 12582912);
  ushort_t* wob = (ushort_t*)(ws + 14680064);
  ushort_t* qb  = (ushort_t*)(ws + 16777216);
  ushort_t* kb  = (ushort_t*)(ws + 25165824);
  ushort_t* vtb = (ushort_t*)(ws + 33554432);
  ushort_t* aob = (ushort_t*)(ws + 41943040);

  hipLaunchKernelGGL(convert_kernel, dim3(8192), dim3(256), 0, stream,
                     x, Wq, Wk, Wv, Wo, xb, wqb, wkb, wvb, wob);
  hipLaunchKernelGGL(qkv_kernel, dim3(768), dim3(256), 0, stream,
                     xb, wqb, wkb, wvb, bq, bk, bv, mask, qb, kb, vtb);
  hipLaunchKernelGGL(attn_kernel, dim3(32, 32), dim3(128), 0, stream,
                     qb, kb, vtb, aob);
  hipLaunchKernelGGL(gemm_o_kernel, dim3(32, 8), dim3(256), 0, stream,
                     aob, wob, bo, (float*)d_out);
}

// Round 12
// 126.425 us; speedup vs baseline: 1.6042x; 1.6042x over previous
//
#include <hip/hip_runtime.h>

#define DEV __device__ __forceinline__

typedef __bf16 bf16x8 __attribute__((ext_vector_type(8)));
typedef __bf16 bf16x4 __attribute__((ext_vector_type(4)));
typedef float f32x4 __attribute__((ext_vector_type(4)));
typedef unsigned u32x4 __attribute__((ext_vector_type(4)));
typedef unsigned short ushort_t;

static constexpr int EMBED = 1024;
static constexpr int NHEAD = 16;
static constexpr int HDIM  = 64;
static constexpr int S_    = 2048;
static constexpr float SCALE_L2E = 0.125f * 1.44269504088896340736f; // (1/sqrt(64))*log2(e)

DEV ushort_t f2bf(float f) {
  unsigned u = __builtin_bit_cast(unsigned, f);
  unsigned r = (u + 0x7fffu + ((u >> 16) & 1u)) >> 16;
  return (ushort_t)r;
}

// async global->LDS, 16B per lane; LDS dest is wave-uniform base + lane*16
#define GLOAD_LDS16(g, l)                                                   \
  __builtin_amdgcn_global_load_lds(                                         \
      (const __attribute__((address_space(1))) unsigned int*)(g),           \
      (__attribute__((address_space(3))) unsigned int*)(l), 16, 0, 0)

// explicit drain of global_load_lds before a publish barrier (semantically
// required anyway; compiler normally emits it before s_barrier)
#define DRAIN_VM() asm volatile("s_waitcnt vmcnt(0)" ::: "memory")

// ---------------------------------------------------------------------------
// fp32 -> bf16 conversion of x and the four weight matrices
// ---------------------------------------------------------------------------
__global__ __launch_bounds__(256) void convert_kernel(
    const float* __restrict__ x,
    const float* __restrict__ wq, const float* __restrict__ wk,
    const float* __restrict__ wv, const float* __restrict__ wo,
    ushort_t* __restrict__ xb, ushort_t* __restrict__ wqb,
    ushort_t* __restrict__ wkb, ushort_t* __restrict__ wvb,
    ushort_t* __restrict__ wob) {
  size_t i = ((size_t)blockIdx.x * blockDim.x + threadIdx.x) * 4;
  const float* src; ushort_t* dst; size_t off;
  if (i < 4194304u)      { src = x;  dst = xb;  off = i; }
  else if (i < 5242880u) { src = wq; dst = wqb; off = i - 4194304u; }
  else if (i < 6291456u) { src = wk; dst = wkb; off = i - 5242880u; }
  else if (i < 7340032u) { src = wv; dst = wvb; off = i - 6291456u; }
  else                   { src = wo; dst = wob; off = i - 7340032u; }
  float4 v = *(const float4*)(src + off);
  ushort4 o;
  o.x = f2bf(v.x); o.y = f2bf(v.y); o.z = f2bf(v.z); o.w = f2bf(v.w);
  *(ushort4*)(dst + off) = o;
}

// ---------------------------------------------------------------------------
// Merged QKV GEMM, 1-D grid of 768 blocks:
//   bid <256 : Q = xb @ Wq^T  -> [B,H,S,D], (acc+bias)*mask*SCALE_L2E
//   bid <512 : K = xb @ Wk^T  -> [B,H,S,D], (acc+bias)*mask
//   else     : V^T (A=Wv, B=xb) -> [B,H,D,S], acc+bias
// 128x128 tile, BK=64, 4 waves; SINGLE-buffer m97 structure: 33 KB LDS ->
// 3 blocks/CU (grid-limited), inter-block overlap hides the barrier drain.
// (R8 proved the attn permlane asm — not this structure — caused R5/R7 reds.)
// ---------------------------------------------------------------------------
__global__ __launch_bounds__(256) void qkv_kernel(
    const ushort_t* __restrict__ xb, const ushort_t* __restrict__ wqb,
    const ushort_t* __restrict__ wkb, const ushort_t* __restrict__ wvb,
    const float* __restrict__ bq, const float* __restrict__ bk,
    const float* __restrict__ bv, const int* __restrict__ mask,
    ushort_t* __restrict__ qo, ushort_t* __restrict__ ko,
    ushort_t* __restrict__ vto) {
  __shared__ __align__(16) unsigned char ldsA[16384];
  __shared__ __align__(16) unsigned char ldsB[16384];
  __shared__ float maskf[2][128];

  const int bid  = blockIdx.x;
  const int tid  = threadIdx.x;
  const int lane = tid & 63;
  const int w    = tid >> 6;
  const int wm   = (w >> 1) * 64;
  const int wn   = (w & 1) * 64;
  const int rl   = lane & 15;
  const int kg   = lane >> 4;

  int mode, ar0, br0;
  const ushort_t *A, *Bm;
  const float* bias;
  if (bid < 512) {
    mode = bid >> 8;                 // 0=Q, 1=K
    int t = bid & 255;
    ar0 = (t & 31) * 128;            // x rows
    br0 = (t >> 5) * 128;            // weight rows
    A = xb; Bm = mode ? wkb : wqb; bias = mode ? bk : bq;
  } else {
    mode = 2;
    int t = bid - 512;
    ar0 = (t & 7) * 128;             // weight rows
    br0 = (t >> 3) * 128;            // x rows
    A = wvb; Bm = xb; bias = bv;
  }

  if (mode < 2) {
    int hl = tid >> 7, sl = tid & 127;
    int m = ar0 + sl;
    int b = m >> 11, s = m & 2047;
    int h = (br0 >> 6) + hl;
    maskf[hl][sl] = (float)mask[((size_t)b * NHEAD + h) * S_ + s];
  }

  f32x4 acc[4][4];
#pragma unroll
  for (int i = 0; i < 4; ++i)
#pragma unroll
    for (int j = 0; j < 4; ++j) acc[i][j] = f32x4{0.f, 0.f, 0.f, 0.f};

  auto STAGE = [&](int kt) {
    const int k0 = kt * 64;
#pragma unroll
    for (int s = 0; s < 8; ++s) {
      const int basev = s * 256 + w * 64;   // wave-uniform
      const int Lb = basev & 1023;
      const int L = Lb + lane;
      const int row = L >> 3;
      const int gu = (L & 7) ^ (row & 7);
      if (s < 4) {
        GLOAD_LDS16(A + (size_t)(ar0 + row) * EMBED + k0 + gu * 8, &ldsA[Lb * 16]);
      } else {
        GLOAD_LDS16(Bm + (size_t)(br0 + row) * EMBED + k0 + gu * 8, &ldsB[Lb * 16]);
      }
    }
  };

  for (int kt = 0; kt < 16; ++kt) {
    if (kt) __syncthreads();          // all waves done reading previous tile
    STAGE(kt);
    DRAIN_VM();                       // my loads landed
    __syncthreads();                  // everyone's loads landed
#pragma unroll
    for (int kk = 0; kk < 2; ++kk) {
      bf16x8 af[4], bfr[4];
#pragma unroll
      for (int mb = 0; mb < 4; ++mb) {
        const int row = wm + mb * 16 + rl;
        const int off = (kk * 64 + kg * 16) ^ ((row & 7) << 4);
        af[mb] = *(const bf16x8*)(ldsA + row * 128 + off);
      }
#pragma unroll
      for (int nb = 0; nb < 4; ++nb) {
        const int row = wn + nb * 16 + rl;
        const int off = (kk * 64 + kg * 16) ^ ((row & 7) << 4);
        bfr[nb] = *(const bf16x8*)(ldsB + row * 128 + off);
      }
#pragma unroll
      for (int mb = 0; mb < 4; ++mb)
#pragma unroll
        for (int nb = 0; nb < 4; ++nb)
          acc[mb][nb] = __builtin_amdgcn_mfma_f32_16x16x32_bf16(
              af[mb], bfr[nb], acc[mb][nb], 0, 0, 0);
    }
  }

  // epilogue — D layout: row(A idx)=(lane>>4)*4+r, col(B idx)=lane&15
#pragma unroll
  for (int mb = 0; mb < 4; ++mb)
#pragma unroll
    for (int nb = 0; nb < 4; ++nb)
#pragma unroll
      for (int r = 0; r < 4; ++r) {
        int row_l = wm + mb * 16 + kg * 4 + r;
        int col_l = wn + nb * 16 + rl;
        float v = acc[mb][nb][r];
        if (mode < 2) {
          int m = ar0 + row_l, n = br0 + col_l;
          v = (v + bias[n]) * maskf[col_l >> 6][row_l];
          if (mode == 0) v *= SCALE_L2E;
          int b = m >> 11, s = m & 2047, h = n >> 6, d = n & 63;
          ushort_t* o = mode ? ko : qo;
          o[(((size_t)(b * NHEAD + h)) * S_ + s) * HDIM + d] = f2bf(v);
        } else {
          int n = ar0 + row_l, m = br0 + col_l;
          v += bias[n];
          int b = m >> 11, s = m & 2047, h = n >> 6, d = n & 63;
          vto[(((size_t)(b * NHEAD + h)) * HDIM + d) * S_ + s] = f2bf(v);
        }
      }
}

// ---------------------------------------------------------------------------
// O projection GEMM: out[m][n] = aob[m][:] . Wo[n][:] + bo[n]  (fp32 out)
// Single-buffer m97 structure (32 KB LDS).
// ---------------------------------------------------------------------------
__global__ __launch_bounds__(256) void gemm_o_kernel(
    const ushort_t* __restrict__ A, const ushort_t* __restrict__ Bm,
    const float* __restrict__ bias, float* __restrict__ outp) {
  __shared__ __align__(16) unsigned char ldsA[16384];
  __shared__ __align__(16) unsigned char ldsB[16384];

  const int tid  = threadIdx.x;
  const int lane = tid & 63;
  const int w    = tid >> 6;
  const int ar0  = blockIdx.x * 128;
  const int br0  = blockIdx.y * 128;
  const int wm   = (w >> 1) * 64;
  const int wn   = (w & 1) * 64;
  const int rl   = lane & 15;
  const int kg   = lane >> 4;

  f32x4 acc[4][4];
#pragma unroll
  for (int i = 0; i < 4; ++i)
#pragma unroll
    for (int j = 0; j < 4; ++j) acc[i][j] = f32x4{0.f, 0.f, 0.f, 0.f};

  auto STAGE = [&](int kt) {
    const int k0 = kt * 64;
#pragma unroll
    for (int s = 0; s < 8; ++s) {
      const int basev = s * 256 + w * 64;
      const int Lb = basev & 1023;
      const int L = Lb + lane;
      const int row = L >> 3;
      const int gu = (L & 7) ^ (row & 7);
      if (s < 4) {
        GLOAD_LDS16(A + (size_t)(ar0 + row) * EMBED + k0 + gu * 8, &ldsA[Lb * 16]);
      } else {
        GLOAD_LDS16(Bm + (size_t)(br0 + row) * EMBED + k0 + gu * 8, &ldsB[Lb * 16]);
      }
    }
  };

  for (int kt = 0; kt < 16; ++kt) {
    if (kt) __syncthreads();
    STAGE(kt);
    DRAIN_VM();
    __syncthreads();
#pragma unroll
    for (int kk = 0; kk < 2; ++kk) {
      bf16x8 af[4], bfr[4];
#pragma unroll
      for (int mb = 0; mb < 4; ++mb) {
        const int row = wm + mb * 16 + rl;
        const int off = (kk * 64 + kg * 16) ^ ((row & 7) << 4);
        af[mb] = *(const bf16x8*)(ldsA + row * 128 + off);
      }
#pragma unroll
      for (int nb = 0; nb < 4; ++nb) {
        const int row = wn + nb * 16 + rl;
        const int off = (kk * 64 + kg * 16) ^ ((row & 7) << 4);
        bfr[nb] = *(const bf16x8*)(ldsB + row * 128 + off);
      }
#pragma unroll
      for (int mb = 0; mb < 4; ++mb)
#pragma unroll
        for (int nb = 0; nb < 4; ++nb)
          acc[mb][nb] = __builtin_amdgcn_mfma_f32_16x16x32_bf16(
              af[mb], bfr[nb], acc[mb][nb], 0, 0, 0);
    }
  }

#pragma unroll
  for (int mb = 0; mb < 4; ++mb)
#pragma unroll
    for (int nb = 0; nb < 4; ++nb)
#pragma unroll
      for (int r = 0; r < 4; ++r) {
        int m = ar0 + wm + mb * 16 + kg * 4 + r;
        int n = br0 + wn + nb * 16 + rl;
        outp[(size_t)m * EMBED + n] = acc[mb][nb][r] + bias[n];
      }
}

// ---------------------------------------------------------------------------
// Flash attention, swapped-QK^T, fixed-exponent softmax:
// logits already base-2 (scale folded into Q); p = exp2(s) overflow-free.
// P -> bf16 (compiler cvt) -> per-wave LDS round-trip into MFMA-A layout
// (R2-proven pattern; packed 8B writes, ^((row&7)<<4) swizzle -> conflict-
// free in 16-lane phase groups). l computed BY MFMA against a ones
// B-operand from the SAME bf16 P fragments as PV -> quantization cancels
// in o/l; no cross-lane shuffles anywhere. No inline-asm data ops.
// grid (bh=32, qt=32); 2 waves x 32 q-rows; K/V^T tiles of 64 keys, dbuf.
// ---------------------------------------------------------------------------
__global__ __launch_bounds__(128) void attn_kernel(
    const ushort_t* __restrict__ qp, const ushort_t* __restrict__ kp,
    const ushort_t* __restrict__ vtp, ushort_t* __restrict__ ao) {
  __shared__ __align__(16) unsigned char ldsK[2][8192];
  __shared__ __align__(16) unsigned char ldsV[2][8192];
  __shared__ __align__(16) unsigned char ldsP[2][4096];

  const int tid  = threadIdx.x;
  const int lane = tid & 63;
  const int w    = tid >> 6;                  // 0..1
  const int bh   = blockIdx.x;
  const int q0   = blockIdx.y * 64 + w * 32;  // wave's q base
  const int rl   = lane & 15;
  const int kg   = lane >> 4;
  const int pswz = (rl & 7) << 4;

  const bf16x8 ones = __builtin_bit_cast(bf16x8,
      u32x4{0x3F803F80u, 0x3F803F80u, 0x3F803F80u, 0x3F803F80u});

  // Q fragments (B-operand): lane (rl,kg) holds Q[q=qb*16+rl][d=kk*32+kg*8..+8]
  bf16x8 qa[2][2];
#pragma unroll
  for (int qb = 0; qb < 2; ++qb)
#pragma unroll
    for (int kk = 0; kk < 2; ++kk)
      qa[qb][kk] = *(const bf16x8*)(qp + ((size_t)bh * S_ + q0 + qb * 16 + rl) * HDIM +
                                    kk * 32 + kg * 8);

  f32x4 o_acc[2][4];
  f32x4 o_l[2];
#pragma unroll
  for (int qb = 0; qb < 2; ++qb) {
#pragma unroll
    for (int nb = 0; nb < 4; ++nb) o_acc[qb][nb] = f32x4{0.f, 0.f, 0.f, 0.f};
    o_l[qb] = f32x4{0.f, 0.f, 0.f, 0.f};
  }

  unsigned char* pb = ldsP[w];

  auto STAGE = [&](int kt, int bsel) {
#pragma unroll
    for (int s = 0; s < 8; ++s) {
      const int Lb = (s & 3) * 128 + w * 64;  // wave-uniform
      const int L = Lb + lane;
      const int row = L >> 3;
      const int gu = (L & 7) ^ (row & 7);
      if (s < 4) {
        GLOAD_LDS16(kp + ((size_t)bh * S_ + (size_t)kt * 64 + row) * HDIM + gu * 8,
                    &ldsK[bsel][Lb * 16]);
      } else {
        GLOAD_LDS16(vtp + ((size_t)bh * HDIM + row) * S_ + (size_t)kt * 64 + gu * 8,
                    &ldsV[bsel][Lb * 16]);
      }
    }
  };

  STAGE(0, 0);
  DRAIN_VM();
  __syncthreads();
  int cb = 0;
  for (int kt = 0; kt < 32; ++kt) {
    if (kt < 31) STAGE(kt + 1, cb ^ 1);

    // QK^T (swapped): sa[qb][nb][r] = S^T[key=nb*16+kg*4+r][q=qb*16+rl]
    f32x4 sa[2][4];
#pragma unroll
    for (int qb = 0; qb < 2; ++qb)
#pragma unroll
      for (int nb = 0; nb < 4; ++nb) sa[qb][nb] = f32x4{0.f, 0.f, 0.f, 0.f};
#pragma unroll
    for (int nb = 0; nb < 4; ++nb) {
      const int row = nb * 16 + rl;
#pragma unroll
      for (int kk = 0; kk < 2; ++kk) {
        bf16x8 kf = *(const bf16x8*)(ldsK[cb] + row * 128 +
                                     ((kk * 64 + kg * 16) ^ ((row & 7) << 4)));
        sa[0][nb] = __builtin_amdgcn_mfma_f32_16x16x32_bf16(kf, qa[0][kk], sa[0][nb], 0, 0, 0);
        sa[1][nb] = __builtin_amdgcn_mfma_f32_16x16x32_bf16(kf, qa[1][kk], sa[1][nb], 0, 0, 0);
      }
    }

    // P = exp2(s) -> bf16, packed 8B writes into per-wave LDS P buffer:
    // row = q = qb*16+rl; byte = key*2 ^ pswz  (key = nb*16+kg*4+r)
#pragma unroll
    for (int qb = 0; qb < 2; ++qb)
#pragma unroll
      for (int nb = 0; nb < 4; ++nb) {
        bf16x4 pk4;
#pragma unroll
        for (int r = 0; r < 4; ++r)
          pk4[r] = (__bf16)__builtin_amdgcn_exp2f(sa[qb][nb][r]);
        *(bf16x4*)(pb + (qb * 16 + rl) * 128 + ((nb * 32 + kg * 8) ^ pswz)) = pk4;
      }
    asm volatile("s_waitcnt lgkmcnt(0)" ::: "memory");
    __builtin_amdgcn_sched_barrier(0);

    // read P back as MFMA-A fragments: lane (rl,kg) row q, keys kk*32+kg*8..+7
    bf16x8 pa[2][2];
#pragma unroll
    for (int qb = 0; qb < 2; ++qb)
#pragma unroll
      for (int kk = 0; kk < 2; ++kk)
        pa[qb][kk] = *(const bf16x8*)(pb + (qb * 16 + rl) * 128 +
                                      ((kk * 64 + kg * 16) ^ pswz));

    // l by MFMA: o_l[qb][r] = sum_k P[q][k]  (same bf16 P as PV -> consistent)
    o_l[0] = __builtin_amdgcn_mfma_f32_16x16x32_bf16(pa[0][0], ones, o_l[0], 0, 0, 0);
    o_l[0] = __builtin_amdgcn_mfma_f32_16x16x32_bf16(pa[0][1], ones, o_l[0], 0, 0, 0);
    o_l[1] = __builtin_amdgcn_mfma_f32_16x16x32_bf16(pa[1][0], ones, o_l[1], 0, 0, 0);
    o_l[1] = __builtin_amdgcn_mfma_f32_16x16x32_bf16(pa[1][1], ones, o_l[1], 0, 0, 0);

    // PV: O[q][d] += P[q][key] * V^T[d][key]
#pragma unroll
    for (int nb = 0; nb < 4; ++nb) {
      const int row = nb * 16 + rl;
#pragma unroll
      for (int kk = 0; kk < 2; ++kk) {
        bf16x8 vb = *(const bf16x8*)(ldsV[cb] + row * 128 +
                                     ((kk * 64 + kg * 16) ^ ((row & 7) << 4)));
        o_acc[0][nb] = __builtin_amdgcn_mfma_f32_16x16x32_bf16(pa[0][kk], vb, o_acc[0][nb], 0, 0, 0);
        o_acc[1][nb] = __builtin_amdgcn_mfma_f32_16x16x32_bf16(pa[1][kk], vb, o_acc[1][nb], 0, 0, 0);
      }
    }

    DRAIN_VM();                       // prefetch landed before publish barrier
    __syncthreads();
    cb ^= 1;
  }

  // epilogue: O[q=qb*16+kg*4+r][d=nb*16+rl] / l[q]; o_l aligned with o_acc
  const int b = bh >> 4, h = bh & 15;
#pragma unroll
  for (int qb = 0; qb < 2; ++qb)
#pragma unroll
    for (int r = 0; r < 4; ++r) {
      float linv = 1.0f / o_l[qb][r];
      const int row = q0 + qb * 16 + kg * 4 + r;
#pragma unroll
      for (int nb = 0; nb < 4; ++nb) {
        float v = o_acc[qb][nb][r] * linv;
        ao[((size_t)b * S_ + row) * EMBED + h * HDIM + nb * 16 + rl] = f2bf(v);
      }
    }
}

// ---------------------------------------------------------------------------
extern "C" void kernel_launch(void* const* d_in, const int* in_sizes, int n_in,
                              void* d_out, int out_size, void* d_ws, size_t ws_size,
                              hipStream_t stream) {
  const float* x    = (const float*)d_in[0];
  const int*   mask = (const int*)d_in[1];
  const float* Wq   = (const float*)d_in[2];
  const float* bq   = (const float*)d_in[3];
  const float* Wk   = (const float*)d_in[4];
  const float* bk   = (const float*)d_in[5];
  const float* Wv   = (const float*)d_in[6];
  const float* bv   = (const float*)d_in[7];
  const float* Wo   = (const float*)d_in[8];
  const float* bo   = (const float*)d_in[9];

  char* ws = (char*)d_ws;
  ushort_t* xb  = (ushort_t*)(ws);
  ushort_t* wqb = (ushort_t*)(ws + 8388608);
  ushort_t* wkb = (ushort_t*)(ws + 10485760);
  ushort_t* wvb = (ushort_t*)(ws + 12582912);
  ushort_t* wob = (ushort_t*)(ws + 14680064);
  ushort_t* qb  = (ushort_t*)(ws + 16777216);
  ushort_t* kb  = (ushort_t*)(ws + 25165824);
  ushort_t* vtb = (ushort_t*)(ws + 33554432);
  ushort_t* aob = (ushort_t*)(ws + 41943040);

  hipLaunchKernelGGL(convert_kernel, dim3(8192), dim3(256), 0, stream,
                     x, Wq, Wk, Wv, Wo, xb, wqb, wkb, wvb, wob);
  hipLaunchKernelGGL(qkv_kernel, dim3(768), dim3(256), 0, stream,
                     xb, wqb, wkb, wvb, bq, bk, bv, mask, qb, kb, vtb);
  hipLaunchKernelGGL(attn_kernel, dim3(32, 32), dim3(128), 0, stream,
                     qb, kb, vtb, aob);
  hipLaunchKernelGGL(gemm_o_kernel, dim3(32, 8), dim3(256), 0, stream,
                     aob, wob, bo, (float*)d_out);
}